// Round 11
// baseline (214.521 us; speedup 1.0000x reference)
//
#include <hip/hip_runtime.h>
#include <hip/hip_bf16.h>

#define Hh 50

typedef __attribute__((ext_vector_type(8))) short bf16x8;
typedef __attribute__((ext_vector_type(4))) int i32x4;
typedef __attribute__((ext_vector_type(4))) float f32x4;
typedef __attribute__((ext_vector_type(16))) float f32x16;

static __device__ __forceinline__ short b16(float x) {
    return __builtin_bit_cast(short, __float2bfloat16(x));
}
static __device__ __forceinline__ bf16x8 cvt8(const float* p) {
    f32x4 a = *(const f32x4*)p;
    f32x4 b = *(const f32x4*)(p + 4);
    bf16x8 r;
    r[0] = b16(a[0]); r[1] = b16(a[1]); r[2] = b16(a[2]); r[3] = b16(a[3]);
    r[4] = b16(b[0]); r[5] = b16(b[1]); r[6] = b16(b[2]); r[7] = b16(b[3]);
    return r;
}
static __device__ __forceinline__ void keep(const bf16x8& v) {
    i32x4 t = __builtin_bit_cast(i32x4, v);
    asm volatile("" :: "v"(t[0]), "v"(t[1]), "v"(t[2]), "v"(t[3]));
}

// -------- Kernel 0: pack wh_w into per-fragment bf16 layout for 32x32x16 B-operand --------
__global__ __launch_bounds__(256) void k_prep(const float* __restrict__ w,
                                              short* __restrict__ o) {
    int t = (int)blockIdx.x * 256 + threadIdx.x;   // 0..8191
    int nt = t >> 10;
    int ks = (t >> 6) & 15;
    int l  = t & 63;
    int col = nt * 32 + (l & 31);
    int k   = ks * 16 + (l >> 5) * 8;
    bf16x8 v = cvt8(w + (size_t)col * 256 + k);
    *(bf16x8*)(o + (size_t)t * 8) = v;
}

// ---------------- Kernel 1: wc_out[4096][256] (f32) = cur @ wc_w^T + wc_b ----------------
__global__ __launch_bounds__(64) void k_wc(const float* __restrict__ cur,
                                           const float* __restrict__ wcw,
                                           const float* __restrict__ wcb,
                                           float* __restrict__ out) {
    int l = threadIdx.x;
    int m0 = (int)(blockIdx.x >> 2) * 16;
    int ntb = (int)(blockIdx.x & 3) * 4;
    int lk = (l >> 4) * 8;

    bf16x8 Af[8];
#pragma unroll
    for (int k = 0; k < 8; k++)
        Af[k] = cvt8(cur + (size_t)(m0 + (l & 15)) * 256 + k * 32 + lk);

#pragma unroll
    for (int nt = 0; nt < 4; nt++) {
        int col = (ntb + nt) * 16 + (l & 15);
        f32x4 a = {0.f, 0.f, 0.f, 0.f};
#pragma unroll
        for (int k = 0; k < 8; k++) {
            bf16x8 Bf = cvt8(wcw + (size_t)col * 256 + k * 32 + lk);
            a = __builtin_amdgcn_mfma_f32_16x16x32_bf16(Af[k], Bf, a, 0, 0, 0);
        }
        float bias = wcb[col];
        int row = m0 + (l >> 4) * 4;
#pragma unroll
        for (int r = 0; r < 4; r++)
            out[(size_t)(row + r) * 256 + col] = a[r] + bias;
    }
}

// ---------------- Kernel 2 (template ablation): fused wh GEMM + sigmoid + alpha*hist ----
// V==0: full round-8 kernel (real output).
// V==3: MFMA removed (loads/staging/trans/shfl kept alive), 64-step loop run TWICE
//       (second pass on the other nh half) -> measures 2x the non-MFMA skeleton.
template <int V>
__global__ __launch_bounds__(256, 4)
void k_main(const float* __restrict__ hist,
            const float* __restrict__ wc_ws,
            const short* __restrict__ whpk,
            const float* __restrict__ whb,
            const float* __restrict__ qtw,
            const float* __restrict__ qtb,
            float* __restrict__ hsum_ws) {
    __shared__ __align__(16) char histA[64 * 512];   // swizzled bf16 [row][256]
    __shared__ float wcrow[256];
    __shared__ float qtl[256];
    __shared__ float alphaP[4][32];
    __shared__ float alphaF[64];

    int tid = threadIdx.x;
    int l = tid & 63;
    int w = tid >> 6;
    int b = (int)(blockIdx.x >> 9);
    int s = (int)(blockIdx.x & 511);

    for (int c = tid; c < 1600; c += 256) {
        int r = c >> 5, g = c & 31;
        bf16x8 v = cvt8(hist + ((size_t)(b * Hh + r) * 512 + s) * 256 + g * 8);
        *(bf16x8*)(&histA[r * 512 + ((g ^ (r & 15)) << 4)]) = v;
    }
    if (tid < 448) {
        int r = 50 + (tid >> 5), g = tid & 31;
        *(f32x4*)(&histA[r * 512 + ((g ^ (r & 15)) << 4)]) = (f32x4){0.f, 0.f, 0.f, 0.f};
    }
    wcrow[tid] = wc_ws[(size_t)(b * 512 + s) * 256 + tid] + whb[tid];
    qtl[tid] = qtw[tid];
    __syncthreads();

    int p = w & 1, nh = w >> 1;

    bf16x8 Af[16];
    {
        int r = p * 32 + (l & 31);
#pragma unroll
        for (int ks = 0; ks < 16; ks++) {
            int g = ks * 2 + (l >> 5);
            Af[ks] = *(const bf16x8*)(&histA[r * 512 + ((g ^ (r & 15)) << 4)]);
        }
    }
    if (V == 3) {
#pragma unroll
        for (int ks = 0; ks < 16; ks++) keep(Af[ks]);   // MFMA gone: keep A-reads live
    }

    float pal[16];
#pragma unroll
    for (int i = 0; i < 16; i++) pal[i] = 0.f;

    const short* wq = whpk + (size_t)l * 8;

    const int NPASS = (V == 3) ? 2 : 1;
#pragma unroll 1
    for (int tw = 0; tw < NPASS; tw++) {
        int nhe = (V == 3) ? (nh ^ tw) : nh;

        bf16x8 Bq[6];
#pragma unroll
        for (int j = 0; j < 6; j++)
            Bq[j] = *(const bf16x8*)(wq + (size_t)(nhe * 64 + j) * 512);

        f32x16 acc;
#pragma unroll
        for (int step = 0; step < 64; step++) {
            int ks = step & 15;
            if (ks == 0) {
#pragma unroll
                for (int i = 0; i < 16; i++) acc[i] = 0.f;
            }
            if (V == 0) {
                acc = __builtin_amdgcn_mfma_f32_32x32x16_bf16(Af[ks], Bq[step % 6], acc, 0, 0, 0);
            } else {
                keep(Bq[step % 6]);                      // keep B-stream live, no MFMA
            }
            if (step + 6 < 64)
                Bq[step % 6] = *(const bf16x8*)(wq + (size_t)(nhe * 64 + step + 6) * 512);
            if (ks == 15) {
                int nt = nhe * 4 + (step >> 4);
                int col = nt * 32 + (l & 31);
                float qv = qtl[col], wb = wcrow[col];
#pragma unroll
                for (int r = 0; r < 16; r++) {
                    float v = acc[r] + wb;
                    float sg = __builtin_amdgcn_rcpf(1.0f + __expf(-v));
                    pal[r] += qv * sg;
                }
            }
        }
    }

#pragma unroll
    for (int r = 0; r < 16; r++) {
        float v = pal[r];
        v += __shfl_xor(v, 1);
        v += __shfl_xor(v, 2);
        v += __shfl_xor(v, 4);
        v += __shfl_xor(v, 8);
        v += __shfl_xor(v, 16);
        if ((l & 31) == 0) {
            int rowIn = (r & 3) + 8 * (r >> 2) + 4 * (l >> 5);
            alphaP[w][rowIn] = v;
        }
    }
    __syncthreads();
    if (tid < Hh) {
        int pp = tid >> 5, ri = tid & 31;
        alphaF[tid] = qtb[0] + alphaP[pp][ri] + alphaP[2 + pp][ri];
    }
    __syncthreads();

    {
        int d = tid;
        float a = 0.f;
#pragma unroll 2
        for (int h = 0; h < Hh; h++) {
            int g = (d >> 3) ^ (h & 15);
            unsigned short u = *(const unsigned short*)(&histA[h * 512 + (g << 4) + (d & 7) * 2]);
            unsigned int x = ((unsigned int)u) << 16;
            a += alphaF[h] * __builtin_bit_cast(float, x);
        }
        hsum_ws[(size_t)(b * 512 + s) * 256 + d] = a;
    }
}

// ---------------- Kernel 3: out[4096][128] (f32) = [cur, hsum] @ wf_w^T + wf_b ----------------
__global__ __launch_bounds__(64) void k_wf(const float* __restrict__ cur,
                                           const float* __restrict__ hsum,
                                           const float* __restrict__ wfw,
                                           const float* __restrict__ wfb,
                                           float* __restrict__ out) {
    int l = threadIdx.x;
    int m0 = (int)(blockIdx.x >> 1) * 16;
    int ntb = (int)(blockIdx.x & 1) * 4;
    int lk = (l >> 4) * 8;

    f32x4 acc[4];
#pragma unroll
    for (int nt = 0; nt < 4; nt++) acc[nt] = (f32x4){0.f, 0.f, 0.f, 0.f};

#pragma unroll
    for (int k = 0; k < 16; k++) {
        int row = m0 + (l & 15);
        bf16x8 Af;
        if (k < 8)
            Af = cvt8(cur + (size_t)row * 256 + k * 32 + lk);
        else
            Af = cvt8(hsum + (size_t)row * 256 + (k - 8) * 32 + lk);
#pragma unroll
        for (int nt = 0; nt < 4; nt++) {
            int col = (ntb + nt) * 16 + (l & 15);
            bf16x8 Bf = cvt8(wfw + (size_t)col * 512 + k * 32 + lk);
            acc[nt] = __builtin_amdgcn_mfma_f32_16x16x32_bf16(Af, Bf, acc[nt], 0, 0, 0);
        }
    }
#pragma unroll
    for (int nt = 0; nt < 4; nt++) {
        int col = (ntb + nt) * 16 + (l & 15);
        float bias = wfb[col];
        int row = m0 + (l >> 4) * 4;
#pragma unroll
        for (int r = 0; r < 4; r++)
            out[(size_t)(row + r) * 128 + col] = acc[nt][r] + bias;
    }
}

extern "C" void kernel_launch(void* const* d_in, const int* in_sizes, int n_in,
                              void* d_out, int out_size, void* d_ws, size_t ws_size,
                              hipStream_t stream) {
    const float* hist = (const float*)d_in[0];
    const float* cur  = (const float*)d_in[1];
    const float* wc_w = (const float*)d_in[2];
    const float* wc_b = (const float*)d_in[3];
    const float* wh_w = (const float*)d_in[4];
    const float* wh_b = (const float*)d_in[5];
    const float* qt_w = (const float*)d_in[6];
    const float* qt_b = (const float*)d_in[7];
    const float* wf_w = (const float*)d_in[8];
    const float* wf_b = (const float*)d_in[9];

    float* wc_ws = (float*)d_ws;                                   // 4 MB
    float* hsum  = (float*)((char*)d_ws + ((size_t)4 << 20));      // 4 MB
    short* whpk  = (short*)((char*)d_ws + ((size_t)8 << 20));      // 128 KB
    float* dummy = (float*)((char*)d_ws + ((size_t)16 << 20));     // 4 MB ablation sink

    k_prep<<<32, 256, 0, stream>>>(wh_w, whpk);
    k_wc<<<1024, 64, 0, stream>>>(cur, wc_w, wc_b, wc_ws);
    k_main<0><<<4096, 256, 0, stream>>>(hist, wc_ws, whpk, wh_b, qt_w, qt_b, hsum);
    k_main<3><<<4096, 256, 0, stream>>>(hist, wc_ws, whpk, wh_b, qt_w, qt_b, dummy);
    k_wf<<<512, 64, 0, stream>>>(cur, hsum, wf_w, wf_b, (float*)d_out);
}

// Round 12
// 129.415 us; speedup vs baseline: 1.6576x; 1.6576x over previous
//
#include <hip/hip_runtime.h>
#include <hip/hip_bf16.h>

#define Hh 50

typedef __attribute__((ext_vector_type(8))) short bf16x8;
typedef __attribute__((ext_vector_type(4))) float f32x4;

static __device__ __forceinline__ short b16(float x) {
    return __builtin_bit_cast(short, __float2bfloat16(x));
}
// convert 8 contiguous f32 to a bf16x8 MFMA fragment
static __device__ __forceinline__ bf16x8 cvt8(const float* p) {
    f32x4 a = *(const f32x4*)p;
    f32x4 b = *(const f32x4*)(p + 4);
    bf16x8 r;
    r[0] = b16(a[0]); r[1] = b16(a[1]); r[2] = b16(a[2]); r[3] = b16(a[3]);
    r[4] = b16(b[0]); r[5] = b16(b[1]); r[6] = b16(b[2]); r[7] = b16(b[3]);
    return r;
}

// -------- Kernel 0: pack wh_w into 16x16x32 B-fragment order --------
// whpk[((p*8+ks)*64+l)*8+j] = bf16(wh_w[p*16+(l&15)][ks*32+(l>>4)*8+j])
__global__ __launch_bounds__(256) void k_prep(const float* __restrict__ w,
                                              short* __restrict__ o) {
    int t = (int)blockIdx.x * 256 + threadIdx.x;   // 0..8191
    int p  = t >> 9;
    int ks = (t >> 6) & 7;
    int l  = t & 63;
    int col = p * 16 + (l & 15);
    int k   = ks * 32 + (l >> 4) * 8;
    bf16x8 v = cvt8(w + (size_t)col * 256 + k);
    *(bf16x8*)(o + (size_t)t * 8) = v;
}

// ---------------- Kernel 1: wc_out[4096][256] (f32) = cur @ wc_w^T + wc_b ----------------
__global__ __launch_bounds__(64) void k_wc(const float* __restrict__ cur,
                                           const float* __restrict__ wcw,
                                           const float* __restrict__ wcb,
                                           float* __restrict__ out) {
    int l = threadIdx.x;
    int m0 = (int)(blockIdx.x >> 2) * 16;
    int ntb = (int)(blockIdx.x & 3) * 4;
    int lk = (l >> 4) * 8;

    bf16x8 Af[8];
#pragma unroll
    for (int k = 0; k < 8; k++)
        Af[k] = cvt8(cur + (size_t)(m0 + (l & 15)) * 256 + k * 32 + lk);

#pragma unroll
    for (int nt = 0; nt < 4; nt++) {
        int col = (ntb + nt) * 16 + (l & 15);
        f32x4 a = {0.f, 0.f, 0.f, 0.f};
#pragma unroll
        for (int k = 0; k < 8; k++) {
            bf16x8 Bf = cvt8(wcw + (size_t)col * 256 + k * 32 + lk);
            a = __builtin_amdgcn_mfma_f32_16x16x32_bf16(Af[k], Bf, a, 0, 0, 0);
        }
        float bias = wcb[col];
        int row = m0 + (l >> 4) * 4;
#pragma unroll
        for (int r = 0; r < 4; r++)
            out[(size_t)(row + r) * 256 + col] = a[r] + bias;
    }
}

// ---------------- Kernel 2: fused wh GEMM + sigmoid + qt dot + alpha*hist ----------------
// Block = (b, s), 256 thr = 4 waves. 64 hist rows (50 real + 14 pad) in swizzled LDS.
// Wave w owns col-panels p = 4w..4w+3 (64 cols). Inner loop: ks outer (8 steps of K=32),
// 16 INDEPENDENT MFMA chains per wave (acc[4 m-tiles][4 nt-tiles], 16x16x32) --
// chain links are separated by 15 other MFMAs so accumulator latency is hidden.
// A and B double-buffered with static indices (full unroll).
__global__ __launch_bounds__(256, 4)
void k_main(const float* __restrict__ hist,
            const float* __restrict__ wc_ws,
            const short* __restrict__ whpk,
            const float* __restrict__ whb,
            const float* __restrict__ qtw,
            const float* __restrict__ qtb,
            float* __restrict__ hsum_ws) {
    __shared__ __align__(16) char histA[64 * 512];   // swizzled bf16 [row][256]
    __shared__ float wcrow[256];                     // wc_out[b,s,:] + wh_b
    __shared__ float qtl[256];
    __shared__ float alphaP[4][64];
    __shared__ float alphaF[64];

    int tid = threadIdx.x;
    int l = tid & 63;
    int w = tid >> 6;
    int b = (int)(blockIdx.x >> 9);
    int s = (int)(blockIdx.x & 511);

    // stage 50 hist rows (f32 -> bf16) into swizzled LDS
    for (int c = tid; c < 1600; c += 256) {
        int r = c >> 5, g = c & 31;
        bf16x8 v = cvt8(hist + ((size_t)(b * Hh + r) * 512 + s) * 256 + g * 8);
        *(bf16x8*)(&histA[r * 512 + ((g ^ (r & 15)) << 4)]) = v;
    }
    // zero pad rows 50..63
    if (tid < 448) {
        int r = 50 + (tid >> 5), g = tid & 31;
        *(f32x4*)(&histA[r * 512 + ((g ^ (r & 15)) << 4)]) = (f32x4){0.f, 0.f, 0.f, 0.f};
    }
    wcrow[tid] = wc_ws[(size_t)(b * 512 + s) * 256 + tid] + whb[tid];
    qtl[tid] = qtw[tid];
    __syncthreads();

    // ---- 16-chain MFMA block ----
    bf16x8 Ab[2][4], Bb[2][4];
    auto LDA = [&](bf16x8(&A)[4], int ks) {
#pragma unroll
        for (int m = 0; m < 4; m++) {
            int rA = m * 16 + (l & 15);
            int g = ks * 4 + (l >> 4);
            A[m] = *(const bf16x8*)(&histA[rA * 512 + ((g ^ (rA & 15)) << 4)]);
        }
    };
    auto LDB = [&](bf16x8(&Bf)[4], int ks) {
#pragma unroll
        for (int nt = 0; nt < 4; nt++) {
            int p = w * 4 + nt;
            Bf[nt] = *(const bf16x8*)(whpk + ((size_t)((p * 8 + ks) * 64 + l)) * 8);
        }
    };

    f32x4 acc[4][4];
#pragma unroll
    for (int m = 0; m < 4; m++)
#pragma unroll
        for (int nt = 0; nt < 4; nt++)
            acc[m][nt] = (f32x4){0.f, 0.f, 0.f, 0.f};

    LDA(Ab[0], 0);
    LDB(Bb[0], 0);
#pragma unroll
    for (int ks = 0; ks < 8; ks++) {
        int cur = ks & 1, nxt = cur ^ 1;
        if (ks < 7) {
            LDA(Ab[nxt], ks + 1);
            LDB(Bb[nxt], ks + 1);
        }
#pragma unroll
        for (int m = 0; m < 4; m++)
#pragma unroll
            for (int nt = 0; nt < 4; nt++)
                acc[m][nt] = __builtin_amdgcn_mfma_f32_16x16x32_bf16(
                    Ab[cur][m], Bb[cur][nt], acc[m][nt], 0, 0, 0);
    }

    // ---- epilogue: sigmoid + qt, per-lane partial over this wave's 64 cols ----
    float pal[4][4];
#pragma unroll
    for (int m = 0; m < 4; m++)
#pragma unroll
        for (int r = 0; r < 4; r++) pal[m][r] = 0.f;

#pragma unroll
    for (int m = 0; m < 4; m++) {
#pragma unroll
        for (int nt = 0; nt < 4; nt++) {
            int col = w * 64 + nt * 16 + (l & 15);
            float qv = qtl[col], wb = wcrow[col];
#pragma unroll
            for (int r = 0; r < 4; r++) {
                float v = acc[m][nt][r] + wb;
                pal[m][r] += qv * __builtin_amdgcn_rcpf(1.0f + __expf(-v));
            }
        }
    }

    // reduce over the 16 lanes holding the 16 cols of each tile
#pragma unroll
    for (int m = 0; m < 4; m++) {
#pragma unroll
        for (int r = 0; r < 4; r++) {
            float v = pal[m][r];
            v += __shfl_xor(v, 1);
            v += __shfl_xor(v, 2);
            v += __shfl_xor(v, 4);
            v += __shfl_xor(v, 8);
            if ((l & 15) == 0)
                alphaP[w][m * 16 + (l >> 4) * 4 + r] = v;
        }
    }
    __syncthreads();
    if (tid < Hh)
        alphaF[tid] = qtb[0] + alphaP[0][tid] + alphaP[1][tid] + alphaP[2][tid] + alphaP[3][tid];
    __syncthreads();

    // history_sum = sum_h alpha[h] * hist[h], from LDS; one f32 column/thread
    {
        int d = tid;
        float a = 0.f;
#pragma unroll 2
        for (int h = 0; h < Hh; h++) {
            int g = (d >> 3) ^ (h & 15);
            unsigned short u = *(const unsigned short*)(&histA[h * 512 + (g << 4) + (d & 7) * 2]);
            unsigned int x = ((unsigned int)u) << 16;
            a += alphaF[h] * __builtin_bit_cast(float, x);
        }
        hsum_ws[(size_t)(b * 512 + s) * 256 + d] = a;
    }
}

// ---------------- Kernel 3: out[4096][128] (f32) = [cur, hsum] @ wf_w^T + wf_b ----------------
__global__ __launch_bounds__(64) void k_wf(const float* __restrict__ cur,
                                           const float* __restrict__ hsum,
                                           const float* __restrict__ wfw,
                                           const float* __restrict__ wfb,
                                           float* __restrict__ out) {
    int l = threadIdx.x;
    int m0 = (int)(blockIdx.x >> 1) * 16;
    int ntb = (int)(blockIdx.x & 1) * 4;
    int lk = (l >> 4) * 8;

    f32x4 acc[4];
#pragma unroll
    for (int nt = 0; nt < 4; nt++) acc[nt] = (f32x4){0.f, 0.f, 0.f, 0.f};

#pragma unroll
    for (int k = 0; k < 16; k++) {
        int row = m0 + (l & 15);
        bf16x8 Af;
        if (k < 8)
            Af = cvt8(cur + (size_t)row * 256 + k * 32 + lk);
        else
            Af = cvt8(hsum + (size_t)row * 256 + (k - 8) * 32 + lk);
#pragma unroll
        for (int nt = 0; nt < 4; nt++) {
            int col = (ntb + nt) * 16 + (l & 15);
            bf16x8 Bf = cvt8(wfw + (size_t)col * 512 + k * 32 + lk);
            acc[nt] = __builtin_amdgcn_mfma_f32_16x16x32_bf16(Af, Bf, acc[nt], 0, 0, 0);
        }
    }
#pragma unroll
    for (int nt = 0; nt < 4; nt++) {
        int col = (ntb + nt) * 16 + (l & 15);
        float bias = wfb[col];
        int row = m0 + (l >> 4) * 4;
#pragma unroll
        for (int r = 0; r < 4; r++)
            out[(size_t)(row + r) * 128 + col] = acc[nt][r] + bias;
    }
}

extern "C" void kernel_launch(void* const* d_in, const int* in_sizes, int n_in,
                              void* d_out, int out_size, void* d_ws, size_t ws_size,
                              hipStream_t stream) {
    const float* hist = (const float*)d_in[0];
    const float* cur  = (const float*)d_in[1];
    const float* wc_w = (const float*)d_in[2];
    const float* wc_b = (const float*)d_in[3];
    const float* wh_w = (const float*)d_in[4];
    const float* wh_b = (const float*)d_in[5];
    const float* qt_w = (const float*)d_in[6];
    const float* qt_b = (const float*)d_in[7];
    const float* wf_w = (const float*)d_in[8];
    const float* wf_b = (const float*)d_in[9];

    float* wc_ws = (float*)d_ws;                                   // 4 MB
    float* hsum  = (float*)((char*)d_ws + ((size_t)4 << 20));      // 4 MB
    short* whpk  = (short*)((char*)d_ws + ((size_t)8 << 20));      // 128 KB

    k_prep<<<32, 256, 0, stream>>>(wh_w, whpk);
    k_wc<<<1024, 64, 0, stream>>>(cur, wc_w, wc_b, wc_ws);
    k_main<<<4096, 256, 0, stream>>>(hist, wc_ws, whpk, wh_b, qt_w, qt_b, hsum);
    k_wf<<<512, 64, 0, stream>>>(cur, hsum, wf_w, wf_b, (float*)d_out);
}